// Round 3
// baseline (411.522 us; speedup 1.0000x reference)
//
#include <hip/hip_runtime.h>
#include <math.h>

#define BH   32
#define LSEQ 4096
#define DK   128
#define DV   128
#define CH   32
#define NC   (LSEQ/CH)

typedef float4 f4;
typedef unsigned short u16;
typedef __attribute__((ext_vector_type(8))) short  bf16x8;   // MFMA A/B frag (8 bf16)
typedef __attribute__((ext_vector_type(4))) float  f32x4;    // MFMA C/D frag

#define MFMA16(a,b,c) __builtin_amdgcn_mfma_f32_16x16x32_bf16((a),(b),(c),0,0,0)

__device__ __forceinline__ float dot4(const f4 a, const f4 b) {
    return a.x*b.x + a.y*b.y + a.z*b.z + a.w*b.w;
}
__device__ __forceinline__ unsigned pk2(float a, float b) {   // 2x fp32 -> packed bf16 (RNE)
    unsigned ua = __builtin_bit_cast(unsigned, a);
    unsigned ub = __builtin_bit_cast(unsigned, b);
    ua = (ua + 0x7FFFu + ((ua >> 16) & 1u)) >> 16;
    ub = (ub + 0x7FFFu + ((ub >> 16) & 1u)) >> 16;
    return (ua & 0xFFFFu) | (ub << 16);
}
__device__ __forceinline__ u16 bf1(float a) {
    unsigned ua = __builtin_bit_cast(unsigned, a);
    ua = (ua + 0x7FFFu + ((ua >> 16) & 1u)) >> 16;
    return (u16)ua;
}
__device__ __forceinline__ unsigned cvtpk(float a, float b) { // HW RNE pack, == pk2 bits
    unsigned r;
    asm("v_cvt_pk_bf16_f32 %0, %1, %2" : "=v"(r) : "v"(a), "v"(b));
    return r;
}

// ---------------------------------------------------------------------------
// Phase 1 (MFMA prep). Math identical to previous rounds. CHANGE: the four
// u16 staging arrays are now written in FRAG-LINEAR layout: for scan-lane l,
// frag f, element e:  flat = f*512 + l*8 + e  holding  X[rowtile*16 + (l&15)]
// [kslice*32 + (l>>4)*8 + e]  -- so scan reads each frag as one coalesced
// 16B/lane dwordx4.
// ---------------------------------------------------------------------------
__global__ __launch_bounds__(256) void prep_kernel(
    const float* __restrict__ q, const float* __restrict__ k, float* __restrict__ v,
    const float* __restrict__ beta,
    u16* __restrict__ qb16, u16* __restrict__ wb16,
    u16* __restrict__ kT16, u16* __restrict__ A16)
{
    __shared__ u16 qn[CH][136];     // bf16 row-major (272B rows, 16B aligned)
    __shared__ u16 kn[CH][136];
    __shared__ u16 vT[DK][40];      // transposed v (no beta), 80B rows
    __shared__ u16 knT[DK][40];     // transposed kn
    __shared__ float Ts[CH][33];    // G -> T -> T'
    __shared__ float Af[CH][33];    // A fp32
    __shared__ u16 Tb[CH][40];      // bf16 T'
    __shared__ float redq[CH][8], redk[CH][8];
    __shared__ float bet[CH], scq[CH], sck[CH];

    const int tid = threadIdx.x;
    const int hh  = blockIdx.x >> 7;
    const int c   = blockIdx.x & (NC-1);
    const size_t rowbase = (size_t)hh * LSEQ + (size_t)c * CH;
    const size_t base    = rowbase * DK;
    const size_t tb      = (size_t)(hh * NC + c);

    const int r = tid >> 3, sub = tid & 7, d0 = sub * 16;
    const int wid = tid >> 6, lane = tid & 63, quad = lane >> 4, m16 = lane & 15;

    // ---- load q,k,v rows; row sum-of-squares ----
    f4 tq[4], tk[4], tv[4];
    float sq = 0.f, sk = 0.f;
#pragma unroll
    for (int m = 0; m < 4; ++m) {
        tq[m] = *(const f4*)(q + base + (size_t)r*DK + d0 + m*4);
        tk[m] = *(const f4*)(k + base + (size_t)r*DK + d0 + m*4);
        tv[m] = *(const f4*)(v + base + (size_t)r*DK + d0 + m*4);
        sq += dot4(tq[m], tq[m]);
        sk += dot4(tk[m], tk[m]);
    }
    redq[r][sub] = sq;
    redk[r][sub] = sk;
    if (tid < CH) bet[tid] = beta[rowbase + tid];
    __syncthreads();
    if (tid < CH) {
        float a = 0.f, b = 0.f;
#pragma unroll
        for (int j = 0; j < 8; ++j) { a += redq[tid][j]; b += redk[tid][j]; }
        scq[tid] = 1.0f / sqrtf(a + 1e-6f);
        sck[tid] = 1.0f / sqrtf(b + 1e-6f);
    }
    __syncthreads();
    const float aq = scq[r], ak = sck[r];
#pragma unroll
    for (int m = 0; m < 4; ++m) {
        tq[m].x *= aq; tq[m].y *= aq; tq[m].z *= aq; tq[m].w *= aq;
        tk[m].x *= ak; tk[m].y *= ak; tk[m].z *= ak; tk[m].w *= ak;
    }
    // qn,kn row-major bf16 LDS + qb16 global (frag-linear)
    {
        uint4 p0, p1;
        p0.x = pk2(tq[0].x,tq[0].y); p0.y = pk2(tq[0].z,tq[0].w);
        p0.z = pk2(tq[1].x,tq[1].y); p0.w = pk2(tq[1].z,tq[1].w);
        p1.x = pk2(tq[2].x,tq[2].y); p1.y = pk2(tq[2].z,tq[2].w);
        p1.z = pk2(tq[3].x,tq[3].y); p1.w = pk2(tq[3].z,tq[3].w);
        *(uint4*)&qn[r][d0]     = p0;  *(uint4*)&qn[r][d0+8] = p1;
        const int qf = ((r>>4)*4 + (sub>>1))*512 + ((r&15) + (sub&1)*32)*8;
        *(uint4*)(qb16 + tb*4096 + qf)       = p0;
        *(uint4*)(qb16 + tb*4096 + qf + 128) = p1;
        uint4 k0, k1;
        k0.x = pk2(tk[0].x,tk[0].y); k0.y = pk2(tk[0].z,tk[0].w);
        k0.z = pk2(tk[1].x,tk[1].y); k0.w = pk2(tk[1].z,tk[1].w);
        k1.x = pk2(tk[2].x,tk[2].y); k1.y = pk2(tk[2].z,tk[2].w);
        k1.z = pk2(tk[3].x,tk[3].y); k1.w = pk2(tk[3].z,tk[3].w);
        *(uint4*)&kn[r][d0]     = k0;  *(uint4*)&kn[r][d0+8] = k1;
    }
    // transposed bf16: knT[d][r], vT[d][r]
#pragma unroll
    for (int m = 0; m < 4; ++m) {
        knT[d0+m*4+0][r] = bf1(tk[m].x); knT[d0+m*4+1][r] = bf1(tk[m].y);
        knT[d0+m*4+2][r] = bf1(tk[m].z); knT[d0+m*4+3][r] = bf1(tk[m].w);
        vT [d0+m*4+0][r] = bf1(tv[m].x); vT [d0+m*4+1][r] = bf1(tv[m].y);
        vT [d0+m*4+2][r] = bf1(tv[m].z); vT [d0+m*4+3][r] = bf1(tv[m].w);
    }
    __syncthreads();

    // ---- kT16 global (frag-linear) from knT ----
    {
        const int d = tid >> 1, jh = (tid & 1) * 16;
        uint4 z0 = *(const uint4*)&knT[d][jh];
        uint4 z1 = *(const uint4*)&knT[d][jh+8];
        const int kf = (d>>4)*512 + ((d&15) + (tid&1)*32)*8;
        *(uint4*)(kT16 + tb*4096 + kf)       = z0;
        *(uint4*)(kT16 + tb*4096 + kf + 128) = z1;
    }
    // ---- MFMA: A = qn kn^T , G = kn kn^T  (wave w -> tile (ti,tj)) ----
    {
        const int ti = wid >> 1, tj = wid & 1;
        f32x4 aA = {0.f,0.f,0.f,0.f}, aG = {0.f,0.f,0.f,0.f};
#pragma unroll
        for (int ks = 0; ks < 4; ++ks) {
            bf16x8 xq = *(const bf16x8*)&qn[ti*16+m16][ks*32 + quad*8];
            bf16x8 xk = *(const bf16x8*)&kn[ti*16+m16][ks*32 + quad*8];
            bf16x8 yk = *(const bf16x8*)&kn[tj*16+m16][ks*32 + quad*8];
            aA = MFMA16(xq, yk, aA);
            aG = MFMA16(xk, yk, aG);
        }
#pragma unroll
        for (int reg = 0; reg < 4; ++reg) {
            Af[ti*16 + quad*4 + reg][tj*16 + m16] = aA[reg];
            Ts[ti*16 + quad*4 + reg][tj*16 + m16] = aG[reg];
        }
    }
    __syncthreads();

    // ---- A16 write (masked, frag-linear) + T init = -strict_tril(diag(b) G) ----
    {
        const int i = r, j0 = sub * 4;
        float a[4];
#pragma unroll
        for (int jj = 0; jj < 4; ++jj)
            a[jj] = (j0+jj <= i) ? Af[i][j0+jj] : 0.f;
        uint2 pa; pa.x = pk2(a[0], a[1]); pa.y = pk2(a[2], a[3]);
        const int af = (i>>4)*512 + ((i&15) + (sub>>1)*16)*8 + (sub&1)*4;
        *(uint2*)(A16 + tb*1024 + af) = pa;
        const float bi = bet[i];
#pragma unroll
        for (int jj = 0; jj < 4; ++jj) {
            const int j = j0 + jj;
            const float gv = Ts[i][j];
            Ts[i][j] = (j < i) ? -bi * gv : 0.f;
        }
    }
    __syncthreads();

    // ---- forward substitution: wave 0, registers + shuffles ----
    if (tid < 32) {
        float rr[32];
#pragma unroll
        for (int i = 0; i < 32; ++i) rr[i] = Ts[i][tid];
#pragma unroll
        for (int i = 1; i < 32; ++i) {
            float t = 0.f;
#pragma unroll
            for (int kk = 0; kk < i; ++kk)
                t += __shfl(rr[i], kk) * rr[kk];
            rr[i] += t;
        }
        const float bj = bet[tid];
#pragma unroll
        for (int i = 0; i < 32; ++i)
            Ts[i][tid] = ((i == tid) ? 1.0f : rr[i]) * bj;   // T' = T diag(b)
    }
    __syncthreads();
    // ---- pack T' -> bf16 ----
    {
        const int i = r, j0 = sub * 4;
        uint2 p; p.x = pk2(Ts[i][j0], Ts[i][j0+1]); p.y = pk2(Ts[i][j0+2], Ts[i][j0+3]);
        *(uint2*)&Tb[i][j0] = p;
    }
    __syncthreads();

    // ---- u0 = T'@v -> v ; w = -(T'@kn) -> wb16 (frag-linear) ----
#pragma unroll
    for (int dt = 0; dt < 2; ++dt)
#pragma unroll
    for (int it = 0; it < 2; ++it) {
        const int drow = wid*32 + dt*16 + m16;
        bf16x8 av  = *(const bf16x8*)&vT[drow][quad*8];
        bf16x8 ak2 = *(const bf16x8*)&knT[drow][quad*8];
        bf16x8 bT  = *(const bf16x8*)&Tb[it*16 + m16][quad*8];
        f32x4 aU = {0.f,0.f,0.f,0.f}, aW = {0.f,0.f,0.f,0.f};
        aU = MFMA16(av,  bT, aU);
        aW = MFMA16(ak2, bT, aW);
        const int ii = it*16 + m16;               // chunk row
        const int dd = wid*32 + dt*16 + quad*4;   // feature col base
        f4 us; us.x = aU[0]; us.y = aU[1]; us.z = aU[2]; us.w = aU[3];
        *(f4*)(v + base + (size_t)ii*DK + dd) = us;
        uint2 pw; pw.x = pk2(-aW[0], -aW[1]); pw.y = pk2(-aW[2], -aW[3]);
        const int wf = (it*4 + wid)*512 + (m16 + (dt*2 + (quad>>1))*16)*8 + (quad&1)*4;
        *(uint2*)(wb16 + tb*4096 + wf) = pw;
    }
}

// ---------------------------------------------------------------------------
// Phase 2: WAVE-PRIVATE scan. One 64-thread block per (dv-group g, head hh)
// chain; NO barriers, NO cross-wave traffic. blockIdx = g*32 + hh so the 8
// g-blocks of a head share an XCD (L2 reuse of the w/q/kT/A fan-out).
// Per chunk (all in one wave):
//   u   = u0 + (-w)@S          8 MFMA (split-k pairs, order == round 2)
//   UB  = in-register C->B transpose of u (cvt_pk + 8 shfl)
//   S  += kT@u                 8 MFMA into 8 reg accumulators
//   o   = q@S_old + A@u        10 MFMA, direct global store
//   SB  = S^T bf16 B-frags for next chunk via wave-private 4KB LDS
//         (8 ds_write_b64 + 4 ds_read_b128, XOR-swizzled, same-wave order)
// All w/q/kT/A frags are coalesced 16B/lane frag-linear global loads,
// reissued for chunk c+1 immediately after their last use in chunk c.
// ---------------------------------------------------------------------------
__global__ __launch_bounds__(64) void scan_kernel(
    const u16* __restrict__ qb16, const u16* __restrict__ wb16,
    const u16* __restrict__ kT16, const u16* __restrict__ A16,
    const float* __restrict__ u0, float* __restrict__ out)
{
    __shared__ u16 STl[16*128];   // 4KB S^T hand-off, wave-private

    const int lane = threadIdx.x;
    const int quad = lane >> 4, m16 = lane & 15;
    const int hh = blockIdx.x & 31, g = blockIdx.x >> 5;

    const u16* wg = wb16 + (size_t)hh * NC * 4096 + lane*8;
    const u16* qg = qb16 + (size_t)hh * NC * 4096 + lane*8;
    const u16* kg = kT16 + (size_t)hh * NC * 4096 + lane*8;
    const u16* Ag = A16  + (size_t)hh * NC * 1024 + lane*8;
    const float* ug = u0 + (size_t)hh * LSEQ * DK + (size_t)(quad*4)*DK + g*16 + m16;
    float* og = out + (size_t)hh * LSEQ * DV + (size_t)(quad*4)*DV + g*16 + m16;

    const int swz = (m16 & 7) << 3;   // u16-index XOR key (byte<<4)

    bf16x8 WA[8], KA[8], QA[8], AA[2];
    f32x4 U0r[2];
    f32x4 SA[8];
    bf16x8 SB[4];
#pragma unroll
    for (int t = 0; t < 8; ++t) SA[t] = (f32x4){0.f,0.f,0.f,0.f};
#pragma unroll
    for (int ks = 0; ks < 4; ++ks) SB[ks] = (bf16x8){};

#define LOADWU(cc) do { \
    const u16* wp_ = wg + (size_t)(cc)*4096; \
    _Pragma("unroll") \
    for (int f = 0; f < 8; ++f) WA[f] = *(const bf16x8*)(wp_ + f*512); \
    const float* up_ = ug + (size_t)(cc)*CH*DK; \
    _Pragma("unroll") \
    for (int r2 = 0; r2 < 4; ++r2) { \
        U0r[0][r2] = up_[(size_t)r2*DK]; \
        U0r[1][r2] = up_[(size_t)(16+r2)*DK]; } \
} while (0)
#define LOADK(cc) do { \
    const u16* kp_ = kg + (size_t)(cc)*4096; \
    _Pragma("unroll") \
    for (int f = 0; f < 8; ++f) KA[f] = *(const bf16x8*)(kp_ + f*512); \
} while (0)
#define LOADQ(cc) do { \
    const u16* qp_ = qg + (size_t)(cc)*4096; \
    _Pragma("unroll") \
    for (int f = 0; f < 8; ++f) QA[f] = *(const bf16x8*)(qp_ + f*512); \
    const u16* ap_ = Ag + (size_t)(cc)*1024; \
    AA[0] = *(const bf16x8*)(ap_); \
    AA[1] = *(const bf16x8*)(ap_ + 512); \
} while (0)

    LOADWU(0); LOADK(0); LOADQ(0);

    for (int c = 0; c < NC; ++c) {
        const int cn = (c + 1 < NC) ? c + 1 : c;

        // ---- u = u0 + (-w)@S_old : split-k pairs (order == round 2) ----
        f32x4 ua0 = U0r[0], ua1 = U0r[1];
        f32x4 ub0 = {0.f,0.f,0.f,0.f}, ub1 = {0.f,0.f,0.f,0.f};
        ua0 = MFMA16(WA[0], SB[0], ua0);  ub0 = MFMA16(WA[1], SB[1], ub0);
        ua0 = MFMA16(WA[2], SB[2], ua0);  ub0 = MFMA16(WA[3], SB[3], ub0);
        ua1 = MFMA16(WA[4], SB[0], ua1);  ub1 = MFMA16(WA[5], SB[1], ub1);
        ua1 = MFMA16(WA[6], SB[2], ua1);  ub1 = MFMA16(WA[7], SB[3], ub1);
        ua0 += ub0;  ua1 += ub1;

        LOADWU(cn);                               // w/u0 for next chunk

        // ---- in-register C->B transpose of u -> UB ----
        const unsigned Wa0 = cvtpk(ua0[0], ua0[1]), Wa1 = cvtpk(ua0[2], ua0[3]);
        const unsigned Wb0 = cvtpk(ua1[0], ua1[1]), Wb1 = cvtpk(ua1[2], ua1[3]);
        const int s0l = ((quad & 1) << 5) + m16, s1l = s0l + 16;
        union { unsigned w[4]; bf16x8 v; } uc;
        {
            const unsigned a0 = __shfl((int)Wa0, s0l), b0 = __shfl((int)Wb0, s0l);
            const unsigned a1 = __shfl((int)Wa1, s0l), b1 = __shfl((int)Wb1, s0l);
            const unsigned a2 = __shfl((int)Wa0, s1l), b2 = __shfl((int)Wb0, s1l);
            const unsigned a3 = __shfl((int)Wa1, s1l), b3 = __shfl((int)Wb1, s1l);
            const bool hi = (quad >= 2);
            uc.w[0] = hi ? b0 : a0; uc.w[1] = hi ? b1 : a1;
            uc.w[2] = hi ? b2 : a2; uc.w[3] = hi ? b3 : a3;
        }
        const bf16x8 UB = uc.v;

        // ---- S += kT @ u ----
#pragma unroll
        for (int t = 0; t < 8; ++t)
            SA[t] = MFMA16(KA[t], UB, SA[t]);

        LOADK(cn);                                // kT for next chunk

        // ---- o = q@S_old + A@u ----
        f32x4 za0 = {0.f,0.f,0.f,0.f}, zb0 = {0.f,0.f,0.f,0.f};
        f32x4 za1 = {0.f,0.f,0.f,0.f}, zb1 = {0.f,0.f,0.f,0.f};
        za0 = MFMA16(QA[0], SB[0], za0);  zb0 = MFMA16(QA[1], SB[1], zb0);
        za0 = MFMA16(QA[2], SB[2], za0);  zb0 = MFMA16(QA[3], SB[3], zb0);
        za1 = MFMA16(QA[4], SB[0], za1);  zb1 = MFMA16(QA[5], SB[1], zb1);
        za1 = MFMA16(QA[6], SB[2], za1);  zb1 = MFMA16(QA[7], SB[3], zb1);
        za0 += zb0;  za1 += zb1;
        za0 = MFMA16(AA[0], UB, za0);
        za1 = MFMA16(AA[1], UB, za1);
        {
            float* o0 = og + (size_t)c * CH * DV;
            o0[0] = za0[0]; o0[DV] = za0[1]; o0[2*DV] = za0[2]; o0[3*DV] = za0[3];
            float* o1 = o0 + (size_t)16 * DV;
            o1[0] = za1[0]; o1[DV] = za1[1]; o1[2*DV] = za1[2]; o1[3*DV] = za1[3];
        }

        LOADQ(cn);                                // q/A for next chunk

        // ---- S^T -> LDS -> SB (wave-private, no barrier) ----
#pragma unroll
        for (int t = 0; t < 8; ++t) {
            uint2 p;
            p.x = cvtpk(SA[t][0], SA[t][1]);
            p.y = cvtpk(SA[t][2], SA[t][3]);
            *(uint2*)&STl[(m16*128 + t*16 + quad*4) ^ swz] = p;
        }
#pragma unroll
        for (int ks = 0; ks < 4; ++ks)
            SB[ks] = *(const bf16x8*)&STl[(m16*128 + ks*32 + quad*8) ^ swz];
    }

    // ---- final state -> out tail (b,h,dk,dv) fp32 ----
    {
        float* sg = out + (size_t)BH*LSEQ*DV
                        + ((size_t)hh*DK + quad*4)*DV + g*16 + m16;
#pragma unroll
        for (int t = 0; t < 8; ++t) {
            float* sp = sg + (size_t)t * 16 * DV;
            sp[0] = SA[t][0]; sp[DV] = SA[t][1]; sp[2*DV] = SA[t][2]; sp[3*DV] = SA[t][3];
        }
    }
#undef LOADQ
#undef LOADK
#undef LOADWU
}

extern "C" void kernel_launch(void* const* d_in, const int* in_sizes, int n_in,
                              void* d_out, int out_size, void* d_ws, size_t ws_size,
                              hipStream_t stream) {
    (void)in_sizes; (void)n_in; (void)out_size; (void)ws_size;
    const float* q = (const float*)d_in[0];
    const float* k = (const float*)d_in[1];
    float* v = (float*)d_in[2];
    const float* beta = (const float*)d_in[3];
    float* out = (float*)d_out;

    const size_t NE = (size_t)BH * LSEQ * DK;
    u16* qb16 = (u16*)d_ws;
    u16* wb16 = qb16 + NE;
    u16* kT16 = wb16 + NE;
    u16* A16  = kT16 + NE;

    prep_kernel<<<dim3(BH*NC), dim3(256), 0, stream>>>(q, k, v, beta, qb16, wb16, kT16, A16);
    scan_kernel<<<dim3(256), dim3(64), 0, stream>>>(qb16, wb16, kT16, A16, v, out);
}